// Round 1
// 85.218 us; speedup vs baseline: 1.0383x; 1.0383x over previous
//
#include <hip/hip_runtime.h>
#include <math.h>

#define NC   19
#define HH   256
#define WW   256
#define NB   4
#define HW   (HH * WW)       // 65536
#define NPIX (NB * HW)       // 262144
#define NQ   (NPIX / 4)      // 65536 pixel-quads
#define CHQ  (HW / 4)        // 16384 float4 per channel-image plane
#define CAP2 121.0f          // (RAD+1)^2 — any value >100 is masked identically

// ---------------------------------------------------------------------------
// Kernel 1: per-pixel channel pass, float4-vectorized (4 pixels/thread).
// Identical per-pixel math to the scalar version (softmax shift-free moments):
//   St = sum e^{t/4}, T1 = sum e^{t/4} t, T2 = sum e^{t/4} s, Ss = sum e^{s/4}
//   ent = ln St - T1/(4 St);  kl = ln Ss - T2/(4 St) - ent
// 4x fewer VMEM instructions at the same 40 MB FETCH; grid = 256 blocks
// (64 blocks/image, blocks never straddle images). bmax is now 256 entries
// (one per 1024-pixel block).
// ---------------------------------------------------------------------------
__global__ __launch_bounds__(256) void k_pixel(
    const float4* __restrict__ student, const float4* __restrict__ teacher,
    float4* __restrict__ entropy, float4* __restrict__ kl,
    uchar4* __restrict__ fg, float* __restrict__ bmax)
{
    const int q  = blockIdx.x * 256 + threadIdx.x;   // 0..65535
    const int b  = q >> 14;                           // 16384 quads per image
    const int rq = q & (CHQ - 1);
    const float4* tb = teacher + (size_t)b * NC * CHQ + rq;
    const float4* sb = student + (size_t)b * NC * CHQ + rq;

    float St[4] = {0.f, 0.f, 0.f, 0.f};
    float T1[4] = {0.f, 0.f, 0.f, 0.f};
    float T2[4] = {0.f, 0.f, 0.f, 0.f};
    float Ss[4] = {0.f, 0.f, 0.f, 0.f};
    float tmx[4] = {-INFINITY, -INFINITY, -INFINITY, -INFINITY};
    int   ax[4] = {0, 0, 0, 0};

#pragma unroll
    for (int c = 0; c < NC; ++c) {
        float4 tv4 = tb[(size_t)c * CHQ];
        float4 sv4 = sb[(size_t)c * CHQ];
        float tvl[4] = {tv4.x, tv4.y, tv4.z, tv4.w};
        float svl[4] = {sv4.x, sv4.y, sv4.z, sv4.w};
#pragma unroll
        for (int l = 0; l < 4; ++l) {
            float t = tvl[l], s = svl[l];
            if (t > tmx[l]) { tmx[l] = t; ax[l] = c; }   // first-max argmax
            float e = __expf(t * 0.25f);
            St[l] += e;
            T1[l] += e * t;
            T2[l] += e * s;
            Ss[l] += __expf(s * 0.25f);
        }
    }

    float4 ent4, kl4;
    uchar4 f4;
    float em = -INFINITY;
#pragma unroll
    for (int l = 0; l < 4; ++l) {
        float rSt = 1.0f / St[l];
        float e = __logf(St[l]) - 0.25f * T1[l] * rSt;
        float k = __logf(Ss[l]) - 0.25f * T2[l] * rSt - e;
        ((float*)&ent4)[l] = e;
        ((float*)&kl4)[l]  = k;
        ((unsigned char*)&f4)[l] = (ax[l] != 0) ? 1 : 0;
        em = fmaxf(em, e);
    }
    entropy[q] = ent4;
    kl[q]      = kl4;
    fg[q]      = f4;

    // per-block (1024-pixel) entropy max
#pragma unroll
    for (int o = 32; o >= 1; o >>= 1) em = fmaxf(em, __shfl_down(em, o, 64));
    __shared__ float red[4];
    int wave = threadIdx.x >> 6, lane = threadIdx.x & 63;
    if (lane == 0) red[wave] = em;
    __syncthreads();
    if (threadIdx.x == 0)
        bmax[blockIdx.x] = fmaxf(fmaxf(red[0], red[1]), fmaxf(red[2], red[3]));
}

// ---------------------------------------------------------------------------
// Kernel 2: 32x32-tile windowed EDT + epilogue, now 512 threads/block
// (8 waves/CU instead of 4 — this kernel is latency-bound at 1 block/CU).
// Windowed min is exact for the result: any entry at distance > 10 gives
// d2 >= 121 > 100 -> mask = 0 either way. Partial sums plain-stored to
// private slots (zero contention); k_final reduces.
// ---------------------------------------------------------------------------
#define TS   32
#define HALO 10
#define FW   (TS + 2 * HALO)  // 52

__global__ __launch_bounds__(512) void k_tile(
    const unsigned char* __restrict__ fg, const float* __restrict__ entropy,
    const float* __restrict__ kl, const float* __restrict__ bmax,
    double* __restrict__ part)
{
    __shared__ float  fgt[FW][FW];
    __shared__ float  vm[TS][FW];
    __shared__ double snum[8], sden[8];

    const int b   = blockIdx.z;
    const int ti0 = blockIdx.y * TS;
    const int tj0 = blockIdx.x * TS;
    const int tid = threadIdx.x;
    const int wave = tid >> 6, lane = tid & 63;
    const unsigned char* fgb = fg + (size_t)b * HW;

    // per-image entropy max from this image's 64 per-block maxima.
    // Every wave butterfly-reduces its own copy — no smem, no extra sync.
    float m = bmax[(b << 6) + lane];
#pragma unroll
    for (int o = 32; o >= 1; o >>= 1) m = fmaxf(m, __shfl_xor(m, o, 64));
    const float em = m;

    // fg tile + halo as float (out-of-image -> 0 == border_value=0)
    for (int l = tid; l < FW * FW; l += 512) {
        int li = l / FW, lj = l - li * FW;
        int gi = ti0 - HALO + li, gj = tj0 - HALO + lj;
        float v = 0.f;
        if (gi >= 0 && gi < HH && gj >= 0 && gj < WW) v = (float)fgb[gi * WW + gj];
        fgt[li][lj] = v;
    }
    __syncthreads();

    // vertical windowed min (branchless); lanes hit consecutive banks
    for (int l = tid; l < TS * FW; l += 512) {
        int i = l / FW, jj = l - i * FW;
        float mn = CAP2;
#pragma unroll
        for (int di = -HALO; di <= HALO; ++di) {
            float fv = fgt[HALO + i + di][jj];
            mn = fminf(mn, (float)(di * di) + (1.0f - fv) * 1000.0f);
        }
        vm[i][jj] = mn;
    }
    __syncthreads();

    double num = 0.0, den = 0.0;
#pragma unroll
    for (int k = 0; k < (TS * TS) / 512; ++k) {      // 2 pixels/thread
        int p = tid + k * 512;
        int i = p >> 5, j = p & (TS - 1);
        float d2 = CAP2;
#pragma unroll
        for (int dj = -HALO; dj <= HALO; ++dj)
            d2 = fminf(d2, (float)(dj * dj) + vm[i][j + HALO + dj]);
        float mask  = (d2 <= 100.0f) ? 1.0f : 0.0f;
        float wdist = __expf(-d2 * 0.02f) * mask;    // exp(-d2/(2*5^2))

        float f  = fgt[HALO + i][HALO + j];
        float up = fgt[HALO + i - 1][HALO + j];
        float dn = fgt[HALO + i + 1][HALO + j];
        float lf = fgt[HALO + i][HALO + j - 1];
        float rt = fgt[HALO + i][HALO + j + 1];
        float mn4 = fminf(fminf(up, dn), fminf(lf, rt));
        float boundary = (f != 0.f && mn4 == 0.f) ? 1.0f : 0.0f;

        float w = wdist * (1.0f + boundary) * mask;
        size_t gidx = (size_t)b * HW + (size_t)(ti0 + i) * WW + (tj0 + j);
        float conf = 0.1f + 0.9f * (1.0f - entropy[gidx] / (em + 1e-8f));
        float tw = w * conf;
        num += (double)(tw * kl[gidx]);
        den += (double)tw;
    }

    // block reduce -> one plain 16B store to this block's private slot
#pragma unroll
    for (int o = 32; o >= 1; o >>= 1) {
        num += __shfl_down(num, o, 64);
        den += __shfl_down(den, o, 64);
    }
    if (lane == 0) { snum[wave] = num; sden[wave] = den; }
    __syncthreads();
    if (tid == 0) {
        double n = 0.0, d = 0.0;
#pragma unroll
        for (int wv = 0; wv < 8; ++wv) { n += snum[wv]; d += sden[wv]; }
        int bid = (blockIdx.z << 6) + (blockIdx.y << 3) + blockIdx.x;  // 0..255
        part[bid * 2 + 0] = n;
        part[bid * 2 + 1] = d;
    }
}

// ---------------------------------------------------------------------------
// Kernel 3: reduce 256 (num,den) partials, emit scalar. No atomics anywhere.
// Cross-kernel visibility of the plain stores is guaranteed by stream order.
// ---------------------------------------------------------------------------
__global__ __launch_bounds__(256) void k_final(
    const double* __restrict__ part, float* __restrict__ out)
{
    const int tid = threadIdx.x;
    double num = part[tid * 2 + 0];
    double den = part[tid * 2 + 1];
#pragma unroll
    for (int o = 32; o >= 1; o >>= 1) {
        num += __shfl_down(num, o, 64);
        den += __shfl_down(den, o, 64);
    }
    __shared__ double snum[4], sden[4];
    int wave = tid >> 6, lane = tid & 63;
    if (lane == 0) { snum[wave] = num; sden[wave] = den; }
    __syncthreads();
    if (tid == 0) {
        num = snum[0] + snum[1] + snum[2] + snum[3];
        den = sden[0] + sden[1] + sden[2] + sden[3];
        out[0] = (float)(16.0 * num / (den + 1e-8));
    }
}

extern "C" void kernel_launch(void* const* d_in, const int* in_sizes, int n_in,
                              void* d_out, int out_size, void* d_ws, size_t ws_size,
                              hipStream_t stream)
{
    const float4* student = (const float4*)d_in[0];
    const float4* teacher = (const float4*)d_in[1];
    float* out = (float*)d_out;

    char* ws = (char*)d_ws;
    double*        part    = (double*)(ws + 0);           // 512 doubles
    float*         bmax    = (float*)(ws + 8192);         // 256 floats
    float4*        entropy = (float4*)(ws + 16384);
    float4*        kl      = (float4*)(ws + 16384 + (size_t)NPIX * 4);
    uchar4*        fg      = (uchar4*)(ws + 16384 + (size_t)NPIX * 8);

    k_pixel<<<NQ / 256, 256, 0, stream>>>(student, teacher, entropy, kl, fg, bmax);
    dim3 g2(WW / TS, HH / TS, NB);
    k_tile<<<g2, 512, 0, stream>>>((const unsigned char*)fg,
                                   (const float*)entropy, (const float*)kl,
                                   bmax, part);
    k_final<<<1, 256, 0, stream>>>(part, out);
}